// Round 5
// baseline (307.360 us; speedup 1.0000x reference)
//
#include <hip/hip_runtime.h>
#include <hip/hip_bf16.h>

#define Bq 4
#define Sq 2048
#define Dq 512
#define Hq 8
#define HDq 64

typedef __attribute__((ext_vector_type(8))) short short8;
typedef __attribute__((ext_vector_type(4))) float f32x4;

#if __has_builtin(__builtin_amdgcn_exp2f)
#define EXP2(x) __builtin_amdgcn_exp2f(x)
#else
#define EXP2(x) exp2f(x)
#endif

// softmax scale folded into Q projection: q_stored = q * 0.125 * log2(e)
#define SCALE2 (0.125f * 1.44269504088896340736f)
#define INV_SCALE2 (5.545177444479562f)

__device__ __forceinline__ short8 cvt8(float4 a, float4 b) {
    union { __hip_bfloat16 h[8]; short8 s; } u;
    u.h[0] = __float2bfloat16(a.x); u.h[1] = __float2bfloat16(a.y);
    u.h[2] = __float2bfloat16(a.z); u.h[3] = __float2bfloat16(a.w);
    u.h[4] = __float2bfloat16(b.x); u.h[5] = __float2bfloat16(b.y);
    u.h[6] = __float2bfloat16(b.z); u.h[7] = __float2bfloat16(b.w);
    return u.s;
}

// ---------------- batched MFMA projection: O = (X @ W^T + bias) * sc, bf16 head layout ----------------
__global__ __launch_bounds__(256, 3)
void proj_kernel(const float* __restrict__ Xv, const float* __restrict__ Xk, const float* __restrict__ Xq,
                 const float* __restrict__ Wv, const float* __restrict__ Wk, const float* __restrict__ Wq,
                 const float* __restrict__ bv, const float* __restrict__ bk, const float* __restrict__ bq,
                 __hip_bfloat16* __restrict__ Ov, __hip_bfloat16* __restrict__ Ok, __hip_bfloat16* __restrict__ Oq) {
    __shared__ alignas(16) short As[128 * 64];
    __shared__ alignas(16) short Bs[128 * 64];

    const int z = blockIdx.z;
    const float* X   = (z == 0) ? Xv : (z == 1) ? Xk : Xq;
    const float* W   = (z == 0) ? Wv : (z == 1) ? Wk : Wq;
    const float* bia = (z == 0) ? bv : (z == 1) ? bk : bq;
    __hip_bfloat16* O = (z == 0) ? Ov : (z == 1) ? Ok : Oq;
    const float sc = (z == 2) ? SCALE2 : 1.0f;

    const int tid  = threadIdx.x;
    const int lane = tid & 63;
    const int w    = tid >> 6;
    const int wr   = w >> 1;
    const int wc   = w & 1;
    const int m0   = blockIdx.y * 128;
    const int n0   = blockIdx.x * 128;
    const int arow = lane & 15;
    const int ag   = lane >> 4;

    f32x4 acc[4][4];
    #pragma unroll
    for (int t = 0; t < 4; ++t)
        #pragma unroll
        for (int u = 0; u < 4; ++u) acc[t][u] = (f32x4){0.f, 0.f, 0.f, 0.f};

    for (int kk = 0; kk < Dq / 64; ++kk) {
        __syncthreads();
        #pragma unroll
        for (int p = 0; p < 4; ++p) {
            int id  = p * 256 + tid;
            int row = id >> 3;
            int c   = id & 7;
            int dst = row * 128 + ((c * 16) ^ ((row & 7) << 4));
            const float* ax = X + (size_t)(m0 + row) * Dq + kk * 64 + c * 8;
            const float* bx = W + (size_t)(n0 + row) * Dq + kk * 64 + c * 8;
            float4 a0 = *(const float4*)ax;
            float4 a1 = *(const float4*)(ax + 4);
            float4 b0 = *(const float4*)bx;
            float4 b1 = *(const float4*)(bx + 4);
            *(short8*)((char*)As + dst) = cvt8(a0, a1);
            *(short8*)((char*)Bs + dst) = cvt8(b0, b1);
        }
        __syncthreads();
        #pragma unroll
        for (int h = 0; h < 2; ++h) {
            short8 af[4], bf[4];
            #pragma unroll
            for (int t = 0; t < 4; ++t) {
                int ra = wr * 64 + t * 16 + arow;
                int rb = wc * 64 + t * 16 + arow;
                af[t] = *(const short8*)((const char*)As + ra * 128 + ((h * 64 + ag * 16) ^ ((ra & 7) << 4)));
                bf[t] = *(const short8*)((const char*)Bs + rb * 128 + ((h * 64 + ag * 16) ^ ((rb & 7) << 4)));
            }
            #pragma unroll
            for (int t = 0; t < 4; ++t)
                #pragma unroll
                for (int u = 0; u < 4; ++u)
                    acc[t][u] = __builtin_amdgcn_mfma_f32_16x16x32_bf16(af[t], bf[u], acc[t][u], 0, 0, 0);
        }
    }

    float biasv[4];
    #pragma unroll
    for (int u = 0; u < 4; ++u) biasv[u] = bia[n0 + wc * 64 + u * 16 + arow];

    #pragma unroll
    for (int t = 0; t < 4; ++t) {
        #pragma unroll
        for (int u = 0; u < 4; ++u) {
            #pragma unroll
            for (int r = 0; r < 4; ++r) {
                int m = m0 + wr * 64 + t * 16 + 4 * ag + r;
                int n = n0 + wc * 64 + u * 16 + arow;
                int b = m >> 11, s = m & 2047;
                int hh = n >> 6, hd = n & 63;
                O[((((size_t)b * Hq + hh) * Sq + s) << 6) + hd] =
                    __float2bfloat16((acc[t][u][r] + biasv[u]) * sc);
            }
        }
    }
}

// ---------------- F^T = (K+V)^T per head: Ft[bh][d][s] ----------------
__global__ __launch_bounds__(256)
void fuse_t_kernel(const __hip_bfloat16* __restrict__ Kh, const __hip_bfloat16* __restrict__ Vh,
                   __hip_bfloat16* __restrict__ Ft) {
    __shared__ float T[64][65];
    const int bh = blockIdx.x >> 5;
    const int st = blockIdx.x & 31;
    const int tid = threadIdx.x;

    #pragma unroll
    for (int p = 0; p < 2; ++p) {
        int idx = p * 256 + tid;
        int r = idx >> 3;
        int c = (idx & 7) * 8;
        size_t g = ((size_t)bh * Sq + st * 64 + r) * 64 + c;
        float4 k4 = *(const float4*)((const char*)Kh + g * 2);
        float4 v4 = *(const float4*)((const char*)Vh + g * 2);
        const __hip_bfloat16* kp = (const __hip_bfloat16*)&k4;
        const __hip_bfloat16* vp = (const __hip_bfloat16*)&v4;
        #pragma unroll
        for (int j = 0; j < 8; ++j)
            T[r][c + j] = __bfloat162float(kp[j]) + __bfloat162float(vp[j]);
    }
    __syncthreads();
    #pragma unroll
    for (int p = 0; p < 2; ++p) {
        int idx = p * 256 + tid;
        int d  = idx >> 3;
        int s8 = (idx & 7) * 8;
        alignas(16) __hip_bfloat16 tmp[8];
        #pragma unroll
        for (int j = 0; j < 8; ++j) tmp[j] = __float2bfloat16(T[s8 + j][d]);
        *(float4*)((char*)Ft + (((size_t)bh * 64 + d) * Sq + st * 64 + s8) * 2) = *(const float4*)tmp;
    }
}

// ---------------- MFMA attention: static softmax, proven P path, prefetch staging ----------------
__global__ __launch_bounds__(256)
void attn_kernel(const __hip_bfloat16* __restrict__ Qh, const __hip_bfloat16* __restrict__ Kh,
                 const __hip_bfloat16* __restrict__ Vh, const __hip_bfloat16* __restrict__ Ft,
                 float* __restrict__ part) {
    __shared__ alignas(16) short Qs[64 * 64];
    __shared__ alignas(16) short Ks[64 * 64];
    __shared__ alignas(16) short Vs[64 * 64];
    __shared__ alignas(16) short Fs[64 * 64];
    __shared__ alignas(16) short Pk[4 * 16 * 64];
    __shared__ alignas(16) short Pv[4 * 16 * 64];
    __shared__ float part_s[4][64];

    const int tid  = threadIdx.x;
    const int lane = tid & 63;
    const int w    = tid >> 6;
    // XCD-chunked swizzle: each XCD owns 128 consecutive logical blocks (4 heads)
    const int lb   = (blockIdx.x & 7) * 128 + (blockIdx.x >> 3);
    const int bh   = lb >> 5;
    const int s0   = (lb & 31) * 64;

    const char* Qbh = (const char*)(Qh + (size_t)bh * Sq * 64);
    const char* Kbh = (const char*)(Kh + (size_t)bh * Sq * 64);
    const char* Vbh = (const char*)(Vh + (size_t)bh * Sq * 64);
    const char* Fbh = (const char*)(Ft + (size_t)bh * 64 * Sq);

    #pragma unroll
    for (int p = 0; p < 2; ++p) {
        int idx = p * 256 + tid;
        int r = idx >> 3;
        int c = idx & 7;
        int swz = (r & 7) << 4;
        float4 q4 = *(const float4*)(Qbh + ((size_t)(s0 + r) * 64 + c * 8) * 2);
        *(float4*)((char*)Qs + r * 128 + ((c * 16) ^ swz)) = q4;
    }
    __syncthreads();

    const int arow = lane & 15;
    const int ag   = lane >> 4;
    const int aswz = (arow & 7) << 4;

    const int qrow = w * 16 + arow;
    short8 qa0 = *(const short8*)((const char*)Qs + qrow * 128 + ((16 * ag) ^ aswz));
    short8 qa1 = *(const short8*)((const char*)Qs + qrow * 128 + ((64 + 16 * ag) ^ aswz));

    char* PkW = (char*)Pk + w * 2048;
    char* PvW = (char*)Pv + w * 2048;

    f32x4 acc_k[4], acc_v[4];
    #pragma unroll
    for (int t = 0; t < 4; ++t) {
        acc_k[t] = (f32x4){0.f, 0.f, 0.f, 0.f};
        acc_v[t] = (f32x4){0.f, 0.f, 0.f, 0.f};
    }
    float lp_k[4] = {0.f, 0.f, 0.f, 0.f};
    float lp_v[4] = {0.f, 0.f, 0.f, 0.f};

    // staging decomposition (per thread, 2 sub-iterations)
    const int sr0 = tid >> 3;           // row 0..31 (p=0) / +32 (p=1)
    const int sc0 = (tid & 7) * 16;     // byte col offset within 128B row
    const int sg  = (tid & 7) * 8;      // element col offset

    // prefetch chunk 0
    float4 rk[2], rv[2], rf[2];
    #pragma unroll
    for (int p = 0; p < 2; ++p) {
        int r = p * 32 + sr0;
        rk[p] = *(const float4*)(Kbh + ((size_t)r * 64 + sg) * 2);
        rv[p] = *(const float4*)(Vbh + ((size_t)r * 64 + sg) * 2);
        rf[p] = *(const float4*)(Fbh + ((size_t)r * Sq + sg) * 2);
    }

    for (int ck = 0; ck < Sq / 64; ++ck) {
        __syncthreads();   // prior chunk's LDS readers done
        #pragma unroll
        for (int p = 0; p < 2; ++p) {
            int r = p * 32 + sr0;
            int dst = r * 128 + (sc0 ^ ((r & 7) << 4));
            *(float4*)((char*)Ks + dst) = rk[p];
            *(float4*)((char*)Vs + dst) = rv[p];
            *(float4*)((char*)Fs + dst) = rf[p];
        }
        // issue next chunk's loads; latency hides under this chunk's compute
        if (ck + 1 < Sq / 64) {
            const int kv1 = (ck + 1) * 64;
            #pragma unroll
            for (int p = 0; p < 2; ++p) {
                int r = p * 32 + sr0;
                rk[p] = *(const float4*)(Kbh + ((size_t)(kv1 + r) * 64 + sg) * 2);
                rv[p] = *(const float4*)(Vbh + ((size_t)(kv1 + r) * 64 + sg) * 2);
                rf[p] = *(const float4*)(Fbh + ((size_t)r * Sq + kv1 + sg) * 2);
            }
        }
        __syncthreads();

        // ---- scores (scale pre-folded into Q) ----
        f32x4 sk[4], sv[4];
        #pragma unroll
        for (int t = 0; t < 4; ++t) {
            sk[t] = (f32x4){0.f, 0.f, 0.f, 0.f};
            sv[t] = (f32x4){0.f, 0.f, 0.f, 0.f};
        }
        #pragma unroll
        for (int t = 0; t < 4; ++t) {
            int brow = t * 16 + arow;
            int bswz = (brow & 7) << 4;
            short8 kb0 = *(const short8*)((const char*)Ks + brow * 128 + ((16 * ag) ^ bswz));
            short8 kb1 = *(const short8*)((const char*)Ks + brow * 128 + ((64 + 16 * ag) ^ bswz));
            short8 vb0 = *(const short8*)((const char*)Vs + brow * 128 + ((16 * ag) ^ bswz));
            short8 vb1 = *(const short8*)((const char*)Vs + brow * 128 + ((64 + 16 * ag) ^ bswz));
            sk[t] = __builtin_amdgcn_mfma_f32_16x16x32_bf16(qa0, kb0, sk[t], 0, 0, 0);
            sk[t] = __builtin_amdgcn_mfma_f32_16x16x32_bf16(qa1, kb1, sk[t], 0, 0, 0);
            sv[t] = __builtin_amdgcn_mfma_f32_16x16x32_bf16(qa0, vb0, sv[t], 0, 0, 0);
            sv[t] = __builtin_amdgcn_mfma_f32_16x16x32_bf16(qa1, vb1, sv[t], 0, 0, 0);
        }

        // ---- static softmax: P = exp2(S), no max tracking ----
        #pragma unroll
        for (int t = 0; t < 4; ++t) {
            #pragma unroll
            for (int r = 0; r < 4; ++r) {
                float pk = EXP2(sk[t][r]);
                float pv = EXP2(sv[t][r]);
                lp_k[r] += pk; lp_v[r] += pv;
                int row = 4 * ag + r;
                int col2 = (t * 16 + arow) * 2;
                int rswz = (row & 7) << 4;
                *(__hip_bfloat16*)(PkW + row * 128 + (col2 ^ rswz)) = __float2bfloat16(pk);
                *(__hip_bfloat16*)(PvW + row * 128 + (col2 ^ rswz)) = __float2bfloat16(pv);
            }
        }
        // no barrier: Pk/Pv are per-wave regions; same-wave DS ops are in-order

        short8 pka0 = *(const short8*)(PkW + arow * 128 + ((16 * ag) ^ aswz));
        short8 pka1 = *(const short8*)(PkW + arow * 128 + ((64 + 16 * ag) ^ aswz));
        short8 pva0 = *(const short8*)(PvW + arow * 128 + ((16 * ag) ^ aswz));
        short8 pva1 = *(const short8*)(PvW + arow * 128 + ((64 + 16 * ag) ^ aswz));
        #pragma unroll
        for (int t = 0; t < 4; ++t) {
            int brow = t * 16 + arow;
            int bswz = (brow & 7) << 4;
            short8 fb0 = *(const short8*)((const char*)Fs + brow * 128 + ((16 * ag) ^ bswz));
            short8 fb1 = *(const short8*)((const char*)Fs + brow * 128 + ((64 + 16 * ag) ^ bswz));
            acc_k[t] = __builtin_amdgcn_mfma_f32_16x16x32_bf16(pka0, fb0, acc_k[t], 0, 0, 0);
            acc_k[t] = __builtin_amdgcn_mfma_f32_16x16x32_bf16(pka1, fb1, acc_k[t], 0, 0, 0);
            acc_v[t] = __builtin_amdgcn_mfma_f32_16x16x32_bf16(pva0, fb0, acc_v[t], 0, 0, 0);
            acc_v[t] = __builtin_amdgcn_mfma_f32_16x16x32_bf16(pva1, fb1, acc_v[t], 0, 0, 0);
        }
    }

    // ---- epilogue: normalize, multiply by q (undo pre-scale), reduce over rows ----
    #pragma unroll
    for (int off = 1; off < 16; off <<= 1) {
        #pragma unroll
        for (int r = 0; r < 4; ++r) {
            lp_k[r] += __shfl_xor(lp_k[r], off);
            lp_v[r] += __shfl_xor(lp_v[r], off);
        }
    }
    float c[4] = {0.f, 0.f, 0.f, 0.f};
    #pragma unroll
    for (int r = 0; r < 4; ++r) {
        float ilk = 1.0f / lp_k[r];
        float ilv = 1.0f / lp_v[r];
        int qr = w * 16 + 4 * ag + r;
        int qswz = (qr & 7) << 4;
        #pragma unroll
        for (int t = 0; t < 4; ++t) {
            float qv = __bfloat162float(*(const __hip_bfloat16*)(
                (const char*)Qs + qr * 128 + (((t * 16 + arow) * 2) ^ qswz)));
            c[t] += (acc_k[t][r] * ilk + acc_v[t][r] * ilv) * qv;
        }
    }
    #pragma unroll
    for (int t = 0; t < 4; ++t) {
        c[t] *= INV_SCALE2;
        c[t] += __shfl_xor(c[t], 16);
        c[t] += __shfl_xor(c[t], 32);
    }
    if (lane < 16) {
        #pragma unroll
        for (int t = 0; t < 4; ++t) part_s[w][t * 16 + lane] = c[t];
    }
    __syncthreads();
    if (tid < 64) {
        float t = part_s[0][tid] + part_s[1][tid] + part_s[2][tid] + part_s[3][tid];
        part[(size_t)lb * 64 + tid] = t;
    }
}

// ---------------- deterministic final reduction ----------------
__global__ void reduce_kernel(const float* __restrict__ part, float* __restrict__ out) {
    int bh = blockIdx.x;
    int d  = threadIdx.x;
    float t = 0.f;
    for (int i = 0; i < 32; ++i)
        t += part[(size_t)(bh * 32 + i) * 64 + d];
    out[bh * 64 + d] = t;
}

extern "C" void kernel_launch(void* const* d_in, const int* in_sizes, int n_in,
                              void* d_out, int out_size, void* d_ws, size_t ws_size,
                              hipStream_t stream) {
    const float* value = (const float*)d_in[0];
    const float* key   = (const float*)d_in[1];
    const float* query = (const float*)d_in[2];
    const float* Wv    = (const float*)d_in[3];
    const float* bv    = (const float*)d_in[4];
    const float* Wk    = (const float*)d_in[5];
    const float* bk    = (const float*)d_in[6];
    const float* Wq    = (const float*)d_in[7];
    const float* bq    = (const float*)d_in[8];
    float* out = (float*)d_out;

    char* w = (char*)d_ws;
    __hip_bfloat16* Qh = (__hip_bfloat16*)(w);
    __hip_bfloat16* Kh = (__hip_bfloat16*)(w + (size_t)8  * 1024 * 1024);
    __hip_bfloat16* Vh = (__hip_bfloat16*)(w + (size_t)16 * 1024 * 1024);
    __hip_bfloat16* Ft = (__hip_bfloat16*)(w + (size_t)24 * 1024 * 1024);
    float*          part = (float*)      (w + (size_t)32 * 1024 * 1024);

    dim3 pg(Dq / 128, (Bq * Sq) / 128, 3);  // (4, 64, 3)
    proj_kernel<<<pg, 256, 0, stream>>>(value, key, query, Wv, Wk, Wq, bv, bk, bq, Vh, Kh, Qh);

    fuse_t_kernel<<<1024, 256, 0, stream>>>(Kh, Vh, Ft);
    attn_kernel<<<1024, 256, 0, stream>>>(Qh, Kh, Vh, Ft, part);
    reduce_kernel<<<32, 64, 0, stream>>>(part, out);
}

// Round 6
// 185.188 us; speedup vs baseline: 1.6597x; 1.6597x over previous
//
#include <hip/hip_runtime.h>
#include <hip/hip_bf16.h>

#define Bq 4
#define Sq 2048
#define Dq 512
#define Hq 8
#define HDq 64

typedef __attribute__((ext_vector_type(8))) short short8;
typedef __attribute__((ext_vector_type(4))) float f32x4;

#if __has_builtin(__builtin_amdgcn_exp2f)
#define EXP2(x) __builtin_amdgcn_exp2f(x)
#else
#define EXP2(x) exp2f(x)
#endif

// softmax scale folded into Q projection: q_stored = q * 0.125 * log2(e)
#define SCALE2 (0.125f * 1.44269504088896340736f)
#define INV_SCALE2 (5.545177444479562f)

__device__ __forceinline__ short8 cvt8(float4 a, float4 b) {
    union { __hip_bfloat16 h[8]; short8 s; } u;
    u.h[0] = __float2bfloat16(a.x); u.h[1] = __float2bfloat16(a.y);
    u.h[2] = __float2bfloat16(a.z); u.h[3] = __float2bfloat16(a.w);
    u.h[4] = __float2bfloat16(b.x); u.h[5] = __float2bfloat16(b.y);
    u.h[6] = __float2bfloat16(b.z); u.h[7] = __float2bfloat16(b.w);
    return u.s;
}

// ---------------- batched MFMA projection: O = (X @ W^T + bias) * sc, bf16 head layout ----------------
__global__ __launch_bounds__(256, 3)
void proj_kernel(const float* __restrict__ Xv, const float* __restrict__ Xk, const float* __restrict__ Xq,
                 const float* __restrict__ Wv, const float* __restrict__ Wk, const float* __restrict__ Wq,
                 const float* __restrict__ bv, const float* __restrict__ bk, const float* __restrict__ bq,
                 __hip_bfloat16* __restrict__ Ov, __hip_bfloat16* __restrict__ Ok, __hip_bfloat16* __restrict__ Oq) {
    __shared__ alignas(16) short As[128 * 64];
    __shared__ alignas(16) short Bs[128 * 64];

    const int z = blockIdx.z;
    const float* X   = (z == 0) ? Xv : (z == 1) ? Xk : Xq;
    const float* W   = (z == 0) ? Wv : (z == 1) ? Wk : Wq;
    const float* bia = (z == 0) ? bv : (z == 1) ? bk : bq;
    __hip_bfloat16* O = (z == 0) ? Ov : (z == 1) ? Ok : Oq;
    const float sc = (z == 2) ? SCALE2 : 1.0f;

    const int tid  = threadIdx.x;
    const int lane = tid & 63;
    const int w    = tid >> 6;
    const int wr   = w >> 1;
    const int wc   = w & 1;
    const int m0   = blockIdx.y * 128;
    const int n0   = blockIdx.x * 128;
    const int arow = lane & 15;
    const int ag   = lane >> 4;

    f32x4 acc[4][4];
    #pragma unroll
    for (int t = 0; t < 4; ++t)
        #pragma unroll
        for (int u = 0; u < 4; ++u) acc[t][u] = (f32x4){0.f, 0.f, 0.f, 0.f};

    for (int kk = 0; kk < Dq / 64; ++kk) {
        __syncthreads();
        #pragma unroll
        for (int p = 0; p < 4; ++p) {
            int id  = p * 256 + tid;
            int row = id >> 3;
            int c   = id & 7;
            int dst = row * 128 + ((c * 16) ^ ((row & 7) << 4));
            const float* ax = X + (size_t)(m0 + row) * Dq + kk * 64 + c * 8;
            const float* bx = W + (size_t)(n0 + row) * Dq + kk * 64 + c * 8;
            float4 a0 = *(const float4*)ax;
            float4 a1 = *(const float4*)(ax + 4);
            float4 b0 = *(const float4*)bx;
            float4 b1 = *(const float4*)(bx + 4);
            *(short8*)((char*)As + dst) = cvt8(a0, a1);
            *(short8*)((char*)Bs + dst) = cvt8(b0, b1);
        }
        __syncthreads();
        #pragma unroll
        for (int h = 0; h < 2; ++h) {
            short8 af[4], bf[4];
            #pragma unroll
            for (int t = 0; t < 4; ++t) {
                int ra = wr * 64 + t * 16 + arow;
                int rb = wc * 64 + t * 16 + arow;
                af[t] = *(const short8*)((const char*)As + ra * 128 + ((h * 64 + ag * 16) ^ ((ra & 7) << 4)));
                bf[t] = *(const short8*)((const char*)Bs + rb * 128 + ((h * 64 + ag * 16) ^ ((rb & 7) << 4)));
            }
            #pragma unroll
            for (int t = 0; t < 4; ++t)
                #pragma unroll
                for (int u = 0; u < 4; ++u)
                    acc[t][u] = __builtin_amdgcn_mfma_f32_16x16x32_bf16(af[t], bf[u], acc[t][u], 0, 0, 0);
        }
    }

    float biasv[4];
    #pragma unroll
    for (int u = 0; u < 4; ++u) biasv[u] = bia[n0 + wc * 64 + u * 16 + arow];

    #pragma unroll
    for (int t = 0; t < 4; ++t) {
        #pragma unroll
        for (int u = 0; u < 4; ++u) {
            #pragma unroll
            for (int r = 0; r < 4; ++r) {
                int m = m0 + wr * 64 + t * 16 + 4 * ag + r;
                int n = n0 + wc * 64 + u * 16 + arow;
                int b = m >> 11, s = m & 2047;
                int hh = n >> 6, hd = n & 63;
                O[((((size_t)b * Hq + hh) * Sq + s) << 6) + hd] =
                    __float2bfloat16((acc[t][u][r] + biasv[u]) * sc);
            }
        }
    }
}

// ---------------- F^T = (K+V)^T per head: Ft[bh][d][s] ----------------
__global__ __launch_bounds__(256)
void fuse_t_kernel(const __hip_bfloat16* __restrict__ Kh, const __hip_bfloat16* __restrict__ Vh,
                   __hip_bfloat16* __restrict__ Ft) {
    __shared__ float T[64][65];
    const int bh = blockIdx.x >> 5;
    const int st = blockIdx.x & 31;
    const int tid = threadIdx.x;

    #pragma unroll
    for (int p = 0; p < 2; ++p) {
        int idx = p * 256 + tid;
        int r = idx >> 3;
        int c = (idx & 7) * 8;
        size_t g = ((size_t)bh * Sq + st * 64 + r) * 64 + c;
        float4 k4 = *(const float4*)((const char*)Kh + g * 2);
        float4 v4 = *(const float4*)((const char*)Vh + g * 2);
        const __hip_bfloat16* kp = (const __hip_bfloat16*)&k4;
        const __hip_bfloat16* vp = (const __hip_bfloat16*)&v4;
        #pragma unroll
        for (int j = 0; j < 8; ++j)
            T[r][c + j] = __bfloat162float(kp[j]) + __bfloat162float(vp[j]);
    }
    __syncthreads();
    #pragma unroll
    for (int p = 0; p < 2; ++p) {
        int idx = p * 256 + tid;
        int d  = idx >> 3;
        int s8 = (idx & 7) * 8;
        alignas(16) __hip_bfloat16 tmp[8];
        #pragma unroll
        for (int j = 0; j < 8; ++j) tmp[j] = __float2bfloat16(T[s8 + j][d]);
        *(float4*)((char*)Ft + (((size_t)bh * 64 + d) * Sq + st * 64 + s8) * 2) = *(const float4*)tmp;
    }
}

// ---------------- MFMA attention: R3 structure + static softmax + XCD swizzle ----------------
__global__ __launch_bounds__(256)
void attn_kernel(const __hip_bfloat16* __restrict__ Qh, const __hip_bfloat16* __restrict__ Kh,
                 const __hip_bfloat16* __restrict__ Vh, const __hip_bfloat16* __restrict__ Ft,
                 float* __restrict__ part) {
    __shared__ alignas(16) short Qs[64 * 64];
    __shared__ alignas(16) short Ks[64 * 64];
    __shared__ alignas(16) short Vs[64 * 64];
    __shared__ alignas(16) short Fs[64 * 64];
    __shared__ alignas(16) short Pk[4 * 16 * 64];
    __shared__ alignas(16) short Pv[4 * 16 * 64];
    __shared__ float part_s[4][64];

    const int tid  = threadIdx.x;
    const int lane = tid & 63;
    const int w    = tid >> 6;
    // XCD-chunked swizzle: each XCD owns 128 consecutive logical blocks (4 heads)
    const int lb   = (blockIdx.x & 7) * 128 + (blockIdx.x >> 3);
    const int bh   = lb >> 5;
    const int s0   = (lb & 31) * 64;

    const char* Qbh = (const char*)(Qh + (size_t)bh * Sq * 64);
    const char* Kbh = (const char*)(Kh + (size_t)bh * Sq * 64);
    const char* Vbh = (const char*)(Vh + (size_t)bh * Sq * 64);
    const char* Fbh = (const char*)(Ft + (size_t)bh * 64 * Sq);

    #pragma unroll
    for (int p = 0; p < 2; ++p) {
        int idx = p * 256 + tid;
        int r = idx >> 3;
        int c = idx & 7;
        int swz = (r & 7) << 4;
        float4 q4 = *(const float4*)(Qbh + ((size_t)(s0 + r) * 64 + c * 8) * 2);
        *(float4*)((char*)Qs + r * 128 + ((c * 16) ^ swz)) = q4;
    }
    __syncthreads();

    const int arow = lane & 15;
    const int ag   = lane >> 4;
    const int aswz = (arow & 7) << 4;

    const int qrow = w * 16 + arow;
    short8 qa0 = *(const short8*)((const char*)Qs + qrow * 128 + ((16 * ag) ^ aswz));
    short8 qa1 = *(const short8*)((const char*)Qs + qrow * 128 + ((64 + 16 * ag) ^ aswz));

    char* PkW = (char*)Pk + w * 2048;
    char* PvW = (char*)Pv + w * 2048;

    f32x4 acc_k[4], acc_v[4];
    #pragma unroll
    for (int t = 0; t < 4; ++t) {
        acc_k[t] = (f32x4){0.f, 0.f, 0.f, 0.f};
        acc_v[t] = (f32x4){0.f, 0.f, 0.f, 0.f};
    }
    float lp_k[4] = {0.f, 0.f, 0.f, 0.f};
    float lp_v[4] = {0.f, 0.f, 0.f, 0.f};

    for (int ck = 0; ck < Sq / 64; ++ck) {
        const int kv0 = ck * 64;
        __syncthreads();   // prior chunk's LDS readers done
        #pragma unroll
        for (int p = 0; p < 2; ++p) {
            int idx = p * 256 + tid;
            int r = idx >> 3;
            int c = idx & 7;
            int swz = (r & 7) << 4;
            float4 k4 = *(const float4*)(Kbh + ((size_t)(kv0 + r) * 64 + c * 8) * 2);
            float4 v4 = *(const float4*)(Vbh + ((size_t)(kv0 + r) * 64 + c * 8) * 2);
            float4 f4 = *(const float4*)(Fbh + ((size_t)r * Sq + kv0 + c * 8) * 2);
            *(float4*)((char*)Ks + r * 128 + ((c * 16) ^ swz)) = k4;
            *(float4*)((char*)Vs + r * 128 + ((c * 16) ^ swz)) = v4;
            *(float4*)((char*)Fs + r * 128 + ((c * 16) ^ swz)) = f4;
        }
        __syncthreads();

        // ---- scores (softmax scale pre-folded into Q) ----
        f32x4 sk[4], sv[4];
        #pragma unroll
        for (int t = 0; t < 4; ++t) {
            sk[t] = (f32x4){0.f, 0.f, 0.f, 0.f};
            sv[t] = (f32x4){0.f, 0.f, 0.f, 0.f};
        }
        #pragma unroll
        for (int t = 0; t < 4; ++t) {
            int brow = t * 16 + arow;
            int bswz = (brow & 7) << 4;
            short8 kb0 = *(const short8*)((const char*)Ks + brow * 128 + ((16 * ag) ^ bswz));
            short8 kb1 = *(const short8*)((const char*)Ks + brow * 128 + ((64 + 16 * ag) ^ bswz));
            short8 vb0 = *(const short8*)((const char*)Vs + brow * 128 + ((16 * ag) ^ bswz));
            short8 vb1 = *(const short8*)((const char*)Vs + brow * 128 + ((64 + 16 * ag) ^ bswz));
            sk[t] = __builtin_amdgcn_mfma_f32_16x16x32_bf16(qa0, kb0, sk[t], 0, 0, 0);
            sk[t] = __builtin_amdgcn_mfma_f32_16x16x32_bf16(qa1, kb1, sk[t], 0, 0, 0);
            sv[t] = __builtin_amdgcn_mfma_f32_16x16x32_bf16(qa0, vb0, sv[t], 0, 0, 0);
            sv[t] = __builtin_amdgcn_mfma_f32_16x16x32_bf16(qa1, vb1, sv[t], 0, 0, 0);
        }

        // ---- static softmax: P = exp2(S), no max tracking ----
        #pragma unroll
        for (int t = 0; t < 4; ++t) {
            #pragma unroll
            for (int r = 0; r < 4; ++r) {
                float pk = EXP2(sk[t][r]);
                float pv = EXP2(sv[t][r]);
                lp_k[r] += pk; lp_v[r] += pv;
                int row = 4 * ag + r;
                int col2 = (t * 16 + arow) * 2;
                int rswz = (row & 7) << 4;
                *(__hip_bfloat16*)(PkW + row * 128 + (col2 ^ rswz)) = __float2bfloat16(pk);
                *(__hip_bfloat16*)(PvW + row * 128 + (col2 ^ rswz)) = __float2bfloat16(pv);
            }
        }
        // no barrier: Pk/Pv are per-wave regions; same-wave DS ops are in-order

        short8 pka0 = *(const short8*)(PkW + arow * 128 + ((16 * ag) ^ aswz));
        short8 pka1 = *(const short8*)(PkW + arow * 128 + ((64 + 16 * ag) ^ aswz));
        short8 pva0 = *(const short8*)(PvW + arow * 128 + ((16 * ag) ^ aswz));
        short8 pva1 = *(const short8*)(PvW + arow * 128 + ((64 + 16 * ag) ^ aswz));
        #pragma unroll
        for (int t = 0; t < 4; ++t) {
            int brow = t * 16 + arow;
            int bswz = (brow & 7) << 4;
            short8 fb0 = *(const short8*)((const char*)Fs + brow * 128 + ((16 * ag) ^ bswz));
            short8 fb1 = *(const short8*)((const char*)Fs + brow * 128 + ((64 + 16 * ag) ^ bswz));
            acc_k[t] = __builtin_amdgcn_mfma_f32_16x16x32_bf16(pka0, fb0, acc_k[t], 0, 0, 0);
            acc_k[t] = __builtin_amdgcn_mfma_f32_16x16x32_bf16(pka1, fb1, acc_k[t], 0, 0, 0);
            acc_v[t] = __builtin_amdgcn_mfma_f32_16x16x32_bf16(pva0, fb0, acc_v[t], 0, 0, 0);
            acc_v[t] = __builtin_amdgcn_mfma_f32_16x16x32_bf16(pva1, fb1, acc_v[t], 0, 0, 0);
        }
    }

    // ---- epilogue: normalize, multiply by q (undo pre-scale), reduce over rows ----
    #pragma unroll
    for (int off = 1; off < 16; off <<= 1) {
        #pragma unroll
        for (int r = 0; r < 4; ++r) {
            lp_k[r] += __shfl_xor(lp_k[r], off);
            lp_v[r] += __shfl_xor(lp_v[r], off);
        }
    }
    float c[4] = {0.f, 0.f, 0.f, 0.f};
    #pragma unroll
    for (int r = 0; r < 4; ++r) {
        float ilk = 1.0f / lp_k[r];
        float ilv = 1.0f / lp_v[r];
        int qr = w * 16 + 4 * ag + r;
        int qswz = (qr & 7) << 4;
        #pragma unroll
        for (int t = 0; t < 4; ++t) {
            float qv = __bfloat162float(*(const __hip_bfloat16*)(
                (const char*)Qs + qr * 128 + (((t * 16 + arow) * 2) ^ qswz)));
            c[t] += (acc_k[t][r] * ilk + acc_v[t][r] * ilv) * qv;
        }
    }
    #pragma unroll
    for (int t = 0; t < 4; ++t) {
        c[t] *= INV_SCALE2;
        c[t] += __shfl_xor(c[t], 16);
        c[t] += __shfl_xor(c[t], 32);
    }
    if (lane < 16) {
        #pragma unroll
        for (int t = 0; t < 4; ++t) part_s[w][t * 16 + lane] = c[t];
    }
    __syncthreads();
    if (tid < 64) {
        float t = part_s[0][tid] + part_s[1][tid] + part_s[2][tid] + part_s[3][tid];
        part[(size_t)lb * 64 + tid] = t;
    }
}

// ---------------- deterministic final reduction ----------------
__global__ void reduce_kernel(const float* __restrict__ part, float* __restrict__ out) {
    int bh = blockIdx.x;
    int d  = threadIdx.x;
    float t = 0.f;
    for (int i = 0; i < 32; ++i)
        t += part[(size_t)(bh * 32 + i) * 64 + d];
    out[bh * 64 + d] = t;
}

extern "C" void kernel_launch(void* const* d_in, const int* in_sizes, int n_in,
                              void* d_out, int out_size, void* d_ws, size_t ws_size,
                              hipStream_t stream) {
    const float* value = (const float*)d_in[0];
    const float* key   = (const float*)d_in[1];
    const float* query = (const float*)d_in[2];
    const float* Wv    = (const float*)d_in[3];
    const float* bv    = (const float*)d_in[4];
    const float* Wk    = (const float*)d_in[5];
    const float* bk    = (const float*)d_in[6];
    const float* Wq    = (const float*)d_in[7];
    const float* bq    = (const float*)d_in[8];
    float* out = (float*)d_out;

    char* w = (char*)d_ws;
    __hip_bfloat16* Qh = (__hip_bfloat16*)(w);
    __hip_bfloat16* Kh = (__hip_bfloat16*)(w + (size_t)8  * 1024 * 1024);
    __hip_bfloat16* Vh = (__hip_bfloat16*)(w + (size_t)16 * 1024 * 1024);
    __hip_bfloat16* Ft = (__hip_bfloat16*)(w + (size_t)24 * 1024 * 1024);
    float*          part = (float*)      (w + (size_t)32 * 1024 * 1024);

    dim3 pg(Dq / 128, (Bq * Sq) / 128, 3);  // (4, 64, 3)
    proj_kernel<<<pg, 256, 0, stream>>>(value, key, query, Wv, Wk, Wq, bv, bk, bq, Vh, Kh, Qh);

    fuse_t_kernel<<<1024, 256, 0, stream>>>(Kh, Vh, Ft);
    attn_kernel<<<1024, 256, 0, stream>>>(Qh, Kh, Vh, Ft, part);
    reduce_kernel<<<32, 64, 0, stream>>>(part, out);
}

// Round 7
// 165.300 us; speedup vs baseline: 1.8594x; 1.1203x over previous
//
#include <hip/hip_runtime.h>
#include <hip/hip_bf16.h>

#define Bq 4
#define Sq 2048
#define Dq 512
#define Hq 8
#define HDq 64

typedef __attribute__((ext_vector_type(8))) short short8;
typedef __attribute__((ext_vector_type(4))) float f32x4;

#if __has_builtin(__builtin_amdgcn_exp2f)
#define EXP2(x) __builtin_amdgcn_exp2f(x)
#else
#define EXP2(x) exp2f(x)
#endif

// softmax scale folded into Q projection: q_stored = q * 0.125 * log2(e)
#define SCALE2 (0.125f * 1.44269504088896340736f)
#define INV_SCALE2 (5.545177444479562f)

__device__ __forceinline__ short8 cvt8(float4 a, float4 b) {
    union { __hip_bfloat16 h[8]; short8 s; } u;
    u.h[0] = __float2bfloat16(a.x); u.h[1] = __float2bfloat16(a.y);
    u.h[2] = __float2bfloat16(a.z); u.h[3] = __float2bfloat16(a.w);
    u.h[4] = __float2bfloat16(b.x); u.h[5] = __float2bfloat16(b.y);
    u.h[6] = __float2bfloat16(b.z); u.h[7] = __float2bfloat16(b.w);
    return u.s;
}

// direct global->LDS async copy, 16B per lane (LDS dest = wave-uniform base + lane*16)
__device__ __forceinline__ void gload16(const void* g, void* l) {
    __builtin_amdgcn_global_load_lds(
        (const __attribute__((address_space(1))) unsigned int*)g,
        (__attribute__((address_space(3))) unsigned int*)l, 16, 0, 0);
}

// ---------------- batched MFMA projection: O = (X @ W^T + bias) * sc, bf16 head layout ----------------
__global__ __launch_bounds__(256, 3)
void proj_kernel(const float* __restrict__ Xv, const float* __restrict__ Xk, const float* __restrict__ Xq,
                 const float* __restrict__ Wv, const float* __restrict__ Wk, const float* __restrict__ Wq,
                 const float* __restrict__ bv, const float* __restrict__ bk, const float* __restrict__ bq,
                 __hip_bfloat16* __restrict__ Ov, __hip_bfloat16* __restrict__ Ok, __hip_bfloat16* __restrict__ Oq) {
    __shared__ alignas(16) short As[128 * 64];
    __shared__ alignas(16) short Bs[128 * 64];

    const int z = blockIdx.z;
    const float* X   = (z == 0) ? Xv : (z == 1) ? Xk : Xq;
    const float* W   = (z == 0) ? Wv : (z == 1) ? Wk : Wq;
    const float* bia = (z == 0) ? bv : (z == 1) ? bk : bq;
    __hip_bfloat16* O = (z == 0) ? Ov : (z == 1) ? Ok : Oq;
    const float sc = (z == 2) ? SCALE2 : 1.0f;

    const int tid  = threadIdx.x;
    const int lane = tid & 63;
    const int w    = tid >> 6;
    const int wr   = w >> 1;
    const int wc   = w & 1;
    const int m0   = blockIdx.y * 128;
    const int n0   = blockIdx.x * 128;
    const int arow = lane & 15;
    const int ag   = lane >> 4;

    f32x4 acc[4][4];
    #pragma unroll
    for (int t = 0; t < 4; ++t)
        #pragma unroll
        for (int u = 0; u < 4; ++u) acc[t][u] = (f32x4){0.f, 0.f, 0.f, 0.f};

    for (int kk = 0; kk < Dq / 64; ++kk) {
        __syncthreads();
        #pragma unroll
        for (int p = 0; p < 4; ++p) {
            int id  = p * 256 + tid;
            int row = id >> 3;
            int c   = id & 7;
            int dst = row * 128 + ((c * 16) ^ ((row & 7) << 4));
            const float* ax = X + (size_t)(m0 + row) * Dq + kk * 64 + c * 8;
            const float* bx = W + (size_t)(n0 + row) * Dq + kk * 64 + c * 8;
            float4 a0 = *(const float4*)ax;
            float4 a1 = *(const float4*)(ax + 4);
            float4 b0 = *(const float4*)bx;
            float4 b1 = *(const float4*)(bx + 4);
            *(short8*)((char*)As + dst) = cvt8(a0, a1);
            *(short8*)((char*)Bs + dst) = cvt8(b0, b1);
        }
        __syncthreads();
        #pragma unroll
        for (int h = 0; h < 2; ++h) {
            short8 af[4], bf[4];
            #pragma unroll
            for (int t = 0; t < 4; ++t) {
                int ra = wr * 64 + t * 16 + arow;
                int rb = wc * 64 + t * 16 + arow;
                af[t] = *(const short8*)((const char*)As + ra * 128 + ((h * 64 + ag * 16) ^ ((ra & 7) << 4)));
                bf[t] = *(const short8*)((const char*)Bs + rb * 128 + ((h * 64 + ag * 16) ^ ((rb & 7) << 4)));
            }
            #pragma unroll
            for (int t = 0; t < 4; ++t)
                #pragma unroll
                for (int u = 0; u < 4; ++u)
                    acc[t][u] = __builtin_amdgcn_mfma_f32_16x16x32_bf16(af[t], bf[u], acc[t][u], 0, 0, 0);
        }
    }

    float biasv[4];
    #pragma unroll
    for (int u = 0; u < 4; ++u) biasv[u] = bia[n0 + wc * 64 + u * 16 + arow];

    #pragma unroll
    for (int t = 0; t < 4; ++t) {
        #pragma unroll
        for (int u = 0; u < 4; ++u) {
            #pragma unroll
            for (int r = 0; r < 4; ++r) {
                int m = m0 + wr * 64 + t * 16 + 4 * ag + r;
                int n = n0 + wc * 64 + u * 16 + arow;
                int b = m >> 11, s = m & 2047;
                int hh = n >> 6, hd = n & 63;
                O[((((size_t)b * Hq + hh) * Sq + s) << 6) + hd] =
                    __float2bfloat16((acc[t][u][r] + biasv[u]) * sc);
            }
        }
    }
}

// ---------------- F^T = (K+V)^T per head: Ft[bh][d][s] ----------------
__global__ __launch_bounds__(256)
void fuse_t_kernel(const __hip_bfloat16* __restrict__ Kh, const __hip_bfloat16* __restrict__ Vh,
                   __hip_bfloat16* __restrict__ Ft) {
    __shared__ float T[64][65];
    const int bh = blockIdx.x >> 5;
    const int st = blockIdx.x & 31;
    const int tid = threadIdx.x;

    #pragma unroll
    for (int p = 0; p < 2; ++p) {
        int idx = p * 256 + tid;
        int r = idx >> 3;
        int c = (idx & 7) * 8;
        size_t g = ((size_t)bh * Sq + st * 64 + r) * 64 + c;
        float4 k4 = *(const float4*)((const char*)Kh + g * 2);
        float4 v4 = *(const float4*)((const char*)Vh + g * 2);
        const __hip_bfloat16* kp = (const __hip_bfloat16*)&k4;
        const __hip_bfloat16* vp = (const __hip_bfloat16*)&v4;
        #pragma unroll
        for (int j = 0; j < 8; ++j)
            T[r][c + j] = __bfloat162float(kp[j]) + __bfloat162float(vp[j]);
    }
    __syncthreads();
    #pragma unroll
    for (int p = 0; p < 2; ++p) {
        int idx = p * 256 + tid;
        int d  = idx >> 3;
        int s8 = (idx & 7) * 8;
        alignas(16) __hip_bfloat16 tmp[8];
        #pragma unroll
        for (int j = 0; j < 8; ++j) tmp[j] = __float2bfloat16(T[s8 + j][d]);
        *(float4*)((char*)Ft + (((size_t)bh * 64 + d) * Sq + st * 64 + s8) * 2) = *(const float4*)tmp;
    }
}

// ---------------- MFMA attention: 512 thr / QBLK=128 / gload_lds staging ----------------
__global__ __launch_bounds__(512, 4)
void attn_kernel(const __hip_bfloat16* __restrict__ Qh, const __hip_bfloat16* __restrict__ Kh,
                 const __hip_bfloat16* __restrict__ Vh, const __hip_bfloat16* __restrict__ Ft,
                 float* __restrict__ part) {
    __shared__ alignas(16) short Qs[128 * 64];   // 16 KB
    __shared__ alignas(16) short Ks[64 * 64];    // 8 KB
    __shared__ alignas(16) short Vs[64 * 64];
    __shared__ alignas(16) short Fs[64 * 64];
    __shared__ alignas(16) short Pk[8 * 16 * 64]; // 16 KB
    __shared__ alignas(16) short Pv[8 * 16 * 64];
    __shared__ float part_s[8][64];

    const int tid  = threadIdx.x;
    const int lane = tid & 63;
    const int w    = tid >> 6;                 // wave 0..7
    // XCD-chunked swizzle: 512 blocks, each XCD owns 64 consecutive logical blocks (2 heads)
    const int lb   = (blockIdx.x & 7) * 64 + (blockIdx.x >> 3);
    const int bh   = lb >> 4;                  // 16 blocks per (b,h)
    const int s0   = (lb & 15) * 128;

    const char* Qbh = (const char*)(Qh + (size_t)bh * Sq * 64);
    const char* Kbh = (const char*)(Kh + (size_t)bh * Sq * 64);
    const char* Vbh = (const char*)(Vh + (size_t)bh * Sq * 64);
    const char* Fbh = (const char*)(Ft + (size_t)bh * 64 * Sq);

    // stage Q tile (128 rows x 64 dims, swizzled)
    #pragma unroll
    for (int p = 0; p < 2; ++p) {
        int idx = p * 512 + tid;
        int r = idx >> 3;
        int c = idx & 7;
        int swz = (r & 7) << 4;
        float4 q4 = *(const float4*)(Qbh + ((size_t)(s0 + r) * 64 + c * 8) * 2);
        *(float4*)((char*)Qs + r * 128 + ((c * 16) ^ swz)) = q4;
    }
    __syncthreads();

    const int arow = lane & 15;
    const int ag   = lane >> 4;
    const int aswz = (arow & 7) << 4;

    const int qrow = w * 16 + arow;
    short8 qa0 = *(const short8*)((const char*)Qs + qrow * 128 + ((16 * ag) ^ aswz));
    short8 qa1 = *(const short8*)((const char*)Qs + qrow * 128 + ((64 + 16 * ag) ^ aswz));

    char* PkW = (char*)Pk + w * 2048;
    char* PvW = (char*)Pv + w * 2048;

    f32x4 acc_k[4], acc_v[4];
    #pragma unroll
    for (int t = 0; t < 4; ++t) {
        acc_k[t] = (f32x4){0.f, 0.f, 0.f, 0.f};
        acc_v[t] = (f32x4){0.f, 0.f, 0.f, 0.f};
    }
    float lp_k[4] = {0.f, 0.f, 0.f, 0.f};
    float lp_v[4] = {0.f, 0.f, 0.f, 0.f};

    // staging geometry: granule g = w*64+lane covers LDS bytes [g*16, g*16+16)
    // LDS linear granule (r, c_lin); source col-granule pre-swizzled: c_src = c_lin ^ (r&7)
    const int sgr = w * 8 + (lane >> 3);            // row 0..63
    const int scs = (lane & 7) ^ (sgr & 7);         // source granule col
    const size_t koff = ((size_t)sgr * 64 + scs * 8) * 2;
    char* ldsK = (char*)Ks + w * 1024;
    char* ldsV = (char*)Vs + w * 1024;
    char* ldsF = (char*)Fs + w * 1024;

    for (int ck = 0; ck < Sq / 64; ++ck) {
        const int kv0 = ck * 64;
        __syncthreads();   // prior chunk's LDS readers done
        gload16(Kbh + (size_t)kv0 * 128 + koff, ldsK);
        gload16(Vbh + (size_t)kv0 * 128 + koff, ldsV);
        gload16(Fbh + ((size_t)sgr * Sq + kv0 + scs * 8) * 2, ldsF);
        __syncthreads();   // barrier drains vmcnt -> staged data visible

        // ---- scores (softmax scale pre-folded into Q) ----
        f32x4 sk[4], sv[4];
        #pragma unroll
        for (int t = 0; t < 4; ++t) {
            sk[t] = (f32x4){0.f, 0.f, 0.f, 0.f};
            sv[t] = (f32x4){0.f, 0.f, 0.f, 0.f};
        }
        #pragma unroll
        for (int t = 0; t < 4; ++t) {
            int brow = t * 16 + arow;
            int bswz = (brow & 7) << 4;
            short8 kb0 = *(const short8*)((const char*)Ks + brow * 128 + ((16 * ag) ^ bswz));
            short8 kb1 = *(const short8*)((const char*)Ks + brow * 128 + ((64 + 16 * ag) ^ bswz));
            short8 vb0 = *(const short8*)((const char*)Vs + brow * 128 + ((16 * ag) ^ bswz));
            short8 vb1 = *(const short8*)((const char*)Vs + brow * 128 + ((64 + 16 * ag) ^ bswz));
            sk[t] = __builtin_amdgcn_mfma_f32_16x16x32_bf16(qa0, kb0, sk[t], 0, 0, 0);
            sk[t] = __builtin_amdgcn_mfma_f32_16x16x32_bf16(qa1, kb1, sk[t], 0, 0, 0);
            sv[t] = __builtin_amdgcn_mfma_f32_16x16x32_bf16(qa0, vb0, sv[t], 0, 0, 0);
            sv[t] = __builtin_amdgcn_mfma_f32_16x16x32_bf16(qa1, vb1, sv[t], 0, 0, 0);
        }

        // ---- static softmax: P = exp2(S) ----
        #pragma unroll
        for (int t = 0; t < 4; ++t) {
            #pragma unroll
            for (int r = 0; r < 4; ++r) {
                float pk = EXP2(sk[t][r]);
                float pv = EXP2(sv[t][r]);
                lp_k[r] += pk; lp_v[r] += pv;
                int row = 4 * ag + r;
                int col2 = (t * 16 + arow) * 2;
                int rswz = (row & 7) << 4;
                *(__hip_bfloat16*)(PkW + row * 128 + (col2 ^ rswz)) = __float2bfloat16(pk);
                *(__hip_bfloat16*)(PvW + row * 128 + (col2 ^ rswz)) = __float2bfloat16(pv);
            }
        }
        // no barrier: Pk/Pv are per-wave regions; same-wave DS ops are in-order

        short8 pka0 = *(const short8*)(PkW + arow * 128 + ((16 * ag) ^ aswz));
        short8 pka1 = *(const short8*)(PkW + arow * 128 + ((64 + 16 * ag) ^ aswz));
        short8 pva0 = *(const short8*)(PvW + arow * 128 + ((16 * ag) ^ aswz));
        short8 pva1 = *(const short8*)(PvW + arow * 128 + ((64 + 16 * ag) ^ aswz));
        #pragma unroll
        for (int t = 0; t < 4; ++t) {
            int brow = t * 16 + arow;
            int bswz = (brow & 7) << 4;
            short8 fb0 = *(const short8*)((const char*)Fs + brow * 128 + ((16 * ag) ^ bswz));
            short8 fb1 = *(const short8*)((const char*)Fs + brow * 128 + ((64 + 16 * ag) ^ bswz));
            acc_k[t] = __builtin_amdgcn_mfma_f32_16x16x32_bf16(pka0, fb0, acc_k[t], 0, 0, 0);
            acc_k[t] = __builtin_amdgcn_mfma_f32_16x16x32_bf16(pka1, fb1, acc_k[t], 0, 0, 0);
            acc_v[t] = __builtin_amdgcn_mfma_f32_16x16x32_bf16(pva0, fb0, acc_v[t], 0, 0, 0);
            acc_v[t] = __builtin_amdgcn_mfma_f32_16x16x32_bf16(pva1, fb1, acc_v[t], 0, 0, 0);
        }
    }

    // ---- epilogue: normalize, multiply by q (undo pre-scale), reduce over rows ----
    #pragma unroll
    for (int off = 1; off < 16; off <<= 1) {
        #pragma unroll
        for (int r = 0; r < 4; ++r) {
            lp_k[r] += __shfl_xor(lp_k[r], off);
            lp_v[r] += __shfl_xor(lp_v[r], off);
        }
    }
    float c[4] = {0.f, 0.f, 0.f, 0.f};
    #pragma unroll
    for (int r = 0; r < 4; ++r) {
        float ilk = 1.0f / lp_k[r];
        float ilv = 1.0f / lp_v[r];
        int qr = w * 16 + 4 * ag + r;
        int qswz = (qr & 7) << 4;
        #pragma unroll
        for (int t = 0; t < 4; ++t) {
            float qv = __bfloat162float(*(const __hip_bfloat16*)(
                (const char*)Qs + qr * 128 + (((t * 16 + arow) * 2) ^ qswz)));
            c[t] += (acc_k[t][r] * ilk + acc_v[t][r] * ilv) * qv;
        }
    }
    #pragma unroll
    for (int t = 0; t < 4; ++t) {
        c[t] *= INV_SCALE2;
        c[t] += __shfl_xor(c[t], 16);
        c[t] += __shfl_xor(c[t], 32);
    }
    if (lane < 16) {
        #pragma unroll
        for (int t = 0; t < 4; ++t) part_s[w][t * 16 + lane] = c[t];
    }
    __syncthreads();
    if (tid < 64) {
        float t = 0.f;
        #pragma unroll
        for (int r = 0; r < 8; ++r) t += part_s[r][tid];
        part[(size_t)lb * 64 + tid] = t;
    }
}

// ---------------- deterministic final reduction ----------------
__global__ void reduce_kernel(const float* __restrict__ part, float* __restrict__ out) {
    int bh = blockIdx.x;     // 0..31
    int d  = threadIdx.x;    // 0..63
    float t = 0.f;
    for (int i = 0; i < 16; ++i)
        t += part[(size_t)(bh * 16 + i) * 64 + d];
    out[bh * 64 + d] = t;
}

extern "C" void kernel_launch(void* const* d_in, const int* in_sizes, int n_in,
                              void* d_out, int out_size, void* d_ws, size_t ws_size,
                              hipStream_t stream) {
    const float* value = (const float*)d_in[0];
    const float* key   = (const float*)d_in[1];
    const float* query = (const float*)d_in[2];
    const float* Wv    = (const float*)d_in[3];
    const float* bv    = (const float*)d_in[4];
    const float* Wk    = (const float*)d_in[5];
    const float* bk    = (const float*)d_in[6];
    const float* Wq    = (const float*)d_in[7];
    const float* bq    = (const float*)d_in[8];
    float* out = (float*)d_out;

    char* w = (char*)d_ws;
    __hip_bfloat16* Qh = (__hip_bfloat16*)(w);
    __hip_bfloat16* Kh = (__hip_bfloat16*)(w + (size_t)8  * 1024 * 1024);
    __hip_bfloat16* Vh = (__hip_bfloat16*)(w + (size_t)16 * 1024 * 1024);
    __hip_bfloat16* Ft = (__hip_bfloat16*)(w + (size_t)24 * 1024 * 1024);
    float*          part = (float*)      (w + (size_t)32 * 1024 * 1024);

    dim3 pg(Dq / 128, (Bq * Sq) / 128, 3);  // (4, 64, 3)
    proj_kernel<<<pg, 256, 0, stream>>>(value, key, query, Wv, Wk, Wq, bv, bk, bq, Vh, Kh, Qh);

    fuse_t_kernel<<<1024, 256, 0, stream>>>(Kh, Vh, Ft);
    attn_kernel<<<512, 512, 0, stream>>>(Qh, Kh, Vh, Ft, part);
    reduce_kernel<<<32, 64, 0, stream>>>(part, out);
}